// Round 5
// baseline (386.203 us; speedup 1.0000x reference)
//
#include <hip/hip_runtime.h>
#include <hip/hip_bf16.h>
#include <math.h>

typedef _Float16 half8 __attribute__((ext_vector_type(8)));
typedef float    f32x4 __attribute__((ext_vector_type(4)));

#define NPTS  50000
#define BATCH 8
#define PT 2          // point-row tiles per wave (32 rows)

// ---------------- weight prep: fp32 -> f16, pi-permuted columns ----------------
// 8 slots of [128 rows o][128 positions pos]. pos=(ks,g,j):
//   k(pos) = ks*32 + 16*(j>>2) + 4*g + (j&3).
// Layer j's D-accumulator registers (after ELU+f16 pack) are directly the
// B-fragment of layer j+1 -- x never leaves registers (verified R2-R4).
// Slot 0: [pe60|pad4|z32|pad32]; 1..6: deform; 7: lin1a (3 rows used).
__global__ void prep_weights_k(const float* __restrict__ w_lin0,
                               const float* __restrict__ w_def,
                               const float* __restrict__ w1a,
                               _Float16* __restrict__ W)
{
    int idx = blockIdx.x * blockDim.x + threadIdx.x;
    if (idx >= 8*128*128) return;
    int slot = idx >> 14;
    int o    = (idx >> 7) & 127;
    int pos  = idx & 127;
    int ks = pos >> 5, l = pos & 31, gg = l >> 3, jj = l & 7;
    int k = ks*32 + 16*(jj>>2) + 4*gg + (jj&3);
    float v = 0.f;
    if (slot == 0) {
        if (k < 60)                 v = w_lin0[o*92 + k];
        else if (k >= 64 && k < 96) v = w_lin0[o*92 + 60 + (k-64)];
    } else if (slot <= 6) {
        v = w_def[(slot-1)*16384 + o*128 + k];
    } else {
        if (o < 3) v = w1a[o*128 + k];
    }
    W[idx] = (_Float16)v;
}

__device__ __forceinline__ float elu1(float v) {
    return (v > 0.f) ? v : (__expf(v) - 1.f);
}

// ---- one layer. ft-level A double-buffer (A[2][4] = 32 VGPR); pack each
// ft-pair's acc into Bout[pt][ft>>1] right after its MFMAs.
template<int NKS, bool DOELU>
__device__ __forceinline__ void layer_step(const unsigned char* __restrict__ Wl,
                                           const half8 (&Bin)[PT][4],
                                           half8 (&Bout)[PT][4],
                                           int voff)
{
    const f32x4 Z = {0.f, 0.f, 0.f, 0.f};
    half8 A[2][4];
    #pragma unroll
    for (int ks = 0; ks < NKS; ++ks)
        A[0][ks] = *(const half8*)(Wl + voff + ks*64);

    f32x4 acc[PT][2];
    #pragma unroll
    for (int ft = 0; ft < 8; ++ft) {
        const int cur = ft & 1, nxt = cur ^ 1;
        if (ft < 7) {   // prefetch next ft panel while computing this one
            #pragma unroll
            for (int ks = 0; ks < NKS; ++ks)
                A[nxt][ks] = *(const half8*)(Wl + voff + (ft+1)*4096 + ks*64);
        }
        #pragma unroll
        for (int pt = 0; pt < PT; ++pt) {
            acc[pt][cur] = __builtin_amdgcn_mfma_f32_16x16x32_f16(
                A[cur][0], Bin[pt][0], Z, 0, 0, 0);
            #pragma unroll
            for (int ks = 1; ks < NKS; ++ks)
                acc[pt][cur] = __builtin_amdgcn_mfma_f32_16x16x32_f16(
                    A[cur][ks], Bin[pt][ks], acc[pt][cur], 0, 0, 0);
        }
        if (cur == 1) {   // pack pair (ft-1, ft) -> Bout ks-slot ft>>1
            #pragma unroll
            for (int pt = 0; pt < PT; ++pt) {
                f32x4 e = acc[pt][0], o = acc[pt][1];
                half8 h;
                #pragma unroll
                for (int q = 0; q < 4; ++q) {
                    float v0 = e[q], v1 = o[q];
                    if (DOELU) { v0 = elu1(v0); v1 = elu1(v1); }
                    h[q]   = (_Float16)v0;
                    h[4+q] = (_Float16)v1;
                }
                Bout[pt][ft >> 1] = h;
            }
        }
    }
}

// ---------------- fused decoder: no LDS, no barriers, 4 waves/block ----------------
// Each wave: 32 rows (4 n x 8 b), all 128 features in registers end-to-end.
// W read straight from L2 (256 KB total, FETCH_SIZE confirms residency).
__global__ __launch_bounds__(256, 4)
void decoder_main(const float* __restrict__ z0,
                  const float* __restrict__ cons,
                  const _Float16* __restrict__ W,
                  const float* __restrict__ w1b,
                  float* __restrict__ out)
{
    const int lane = threadIdx.x & 63;
    const int wid  = threadIdx.x >> 6;
    const int p = lane & 15;
    const int g = lane >> 4;
    const int n0 = blockIdx.x * 16 + wid * 4;   // 3125 blocks * 16 n = 50000 exactly
    const int voff = p*256 + g*16;

    const f32x4 Z = {0.f, 0.f, 0.f, 0.f};

    // ---- build layer-0 B-fragments (pi-position order), K=96 -> ks 0..2 ----
    half8 B1[PT][4], B2[PT][4];
    #pragma unroll
    for (int pt = 0; pt < PT; ++pt) {
        const int lrow = pt*16 + p;
        const int n = n0 + (lrow >> 3);
        const int b = lrow & 7;
        float c0 = cons[n*3+0], c1 = cons[n*3+1], c2 = cons[n*3+2];
        #pragma unroll
        for (int ks = 0; ks < 2; ++ks) {
            half8 h;
            #pragma unroll
            for (int j = 0; j < 8; ++j) {
                int k = ks*32 + 16*(j>>2) + 4*g + (j&3);
                float v = 0.f;
                if (k < 60) {
                    int c = k/20, rem = k%20, i = rem%10;
                    float f  = exp2f(7.f * (1.f - (float)i * (1.f/9.f)));  // const-folded
                    float cc = (c == 0) ? c0 : (c == 1) ? c1 : c2;
                    float a  = cc * f;
                    v = (rem < 10) ? __sinf(a) : __cosf(a);
                }
                h[j] = (_Float16)v;
            }
            B1[pt][ks] = h;
        }
        half8 hz;
        #pragma unroll
        for (int j = 0; j < 8; ++j)
            hz[j] = (_Float16)z0[b*32 + 16*(j>>2) + 4*g + (j&3)];
        B1[pt][2] = hz;
    }

    const unsigned char* Wb = (const unsigned char*)W;

    // ---- 7 layers, explicit ping-pong (static indexing only) ----
    layer_step<3, false>(Wb,            B1, B2, voff);   // lin0, K=96
    layer_step<4, true >(Wb + 1*32768,  B2, B1, voff);
    layer_step<4, true >(Wb + 2*32768,  B1, B2, voff);
    layer_step<4, true >(Wb + 3*32768,  B2, B1, voff);
    layer_step<4, true >(Wb + 4*32768,  B1, B2, voff);
    layer_step<4, true >(Wb + 5*32768,  B2, B1, voff);
    layer_step<4, true >(Wb + 6*32768,  B1, B2, voff);   // final acts in B2

    // ---- lin1a: 16 output rows (3 used), K=128 ----
    f32x4 a1[PT];
    {
        const unsigned char* W7 = Wb + 7*32768;
        half8 A7[4];
        #pragma unroll
        for (int ks = 0; ks < 4; ++ks)
            A7[ks] = *(const half8*)(W7 + voff + ks*64);
        #pragma unroll
        for (int pt = 0; pt < PT; ++pt)
            a1[pt] = __builtin_amdgcn_mfma_f32_16x16x32_f16(A7[0], B2[pt][0], Z, 0, 0, 0);
        #pragma unroll
        for (int ks = 1; ks < 4; ++ks)
            #pragma unroll
            for (int pt = 0; pt < PT; ++pt)
                a1[pt] = __builtin_amdgcn_mfma_f32_16x16x32_f16(A7[ks], B2[pt][ks], a1[pt], 0, 0, 0);
    }

    // ---- ELU + lin1b (3x3) + stores, in-register (g==0 lanes own feats 0..3) ----
    if (g == 0) {
        float b00=w1b[0],b01=w1b[1],b02=w1b[2];
        float b10=w1b[3],b11=w1b[4],b12=w1b[5];
        float b20=w1b[6],b21=w1b[7],b22=w1b[8];
        #pragma unroll
        for (int pt = 0; pt < PT; ++pt) {
            int row = pt*16 + p;
            int n = n0 + (row >> 3);
            int b = row & 7;
            float r0 = elu1(a1[pt][0]);
            float r1 = elu1(a1[pt][1]);
            float r2 = elu1(a1[pt][2]);
            int obase = (b*NPTS + n)*3;
            float rv0 = b00*r0 + b01*r1 + b02*r2;
            float rv1 = b10*r0 + b11*r1 + b12*r2;
            float rv2 = b20*r0 + b21*r1 + b22*r2;
            out[obase+0] = cons[n*3+0] + rv0;
            out[obase+1] = cons[n*3+1] + rv1;
            out[obase+2] = cons[n*3+2] + rv2;
            out[BATCH*NPTS*3 + obase+0] = rv0;
            out[BATCH*NPTS*3 + obase+1] = rv1;
            out[BATCH*NPTS*3 + obase+2] = rv2;
        }
    }
}

extern "C" void kernel_launch(void* const* d_in, const int* in_sizes, int n_in,
                              void* d_out, int out_size, void* d_ws, size_t ws_size,
                              hipStream_t stream)
{
    const float* z0     = (const float*)d_in[0];
    const float* cons   = (const float*)d_in[1];
    const float* w_lin0 = (const float*)d_in[2];
    const float* w_def  = (const float*)d_in[3];
    const float* w1a    = (const float*)d_in[4];
    const float* w1b    = (const float*)d_in[5];
    _Float16* W = (_Float16*)d_ws;   // 8 slots * 16384 f16 = 256 KB

    prep_weights_k<<<512, 256, 0, stream>>>(w_lin0, w_def, w1a, W);
    decoder_main<<<NPTS/16, 256, 0, stream>>>(z0, cons, W, w1b, (float*)d_out);
}